// Round 4
// baseline (223.241 us; speedup 1.0000x reference)
//
#include <hip/hip_runtime.h>

#define MAX_REL 16
#define NTAB    33          // 2*MAX_REL+1
#define B       4
#define H       8
#define LQ      1024
#define DH      64
#define KLEN    1024
#define QTILE   16          // q rows per block (4 per wave)
#define PRS     48          // pr row stride (floats)
#define REPS    4           // DIAGNOSTIC: re-store output 4x (idempotent) so the
                            // kernel outlasts the 80us harness fills and shows up
                            // in rocprof top-5 with its own counters.

typedef short s16x8 __attribute__((ext_vector_type(8)));   // 8 bf16 (4 VGPRs)
typedef float f32x4 __attribute__((ext_vector_type(4)));   // MFMA acc / nt-store vec

// round-to-nearest-even f32 -> bf16
static __device__ __forceinline__ short f2bf(float f) {
    unsigned u = __float_as_uint(f);
    unsigned r = (u + 0x7FFFu + ((u >> 16) & 1u)) >> 16;
    return (short)r;
}

// One block = (b, h, 16 q-rows); 4 waves. See R3 for structure notes.
// DIAGNOSTIC build: phase 3 wrapped in REPS loop with a memory-clobber so the
// compiler cannot eliminate the repeated (identical-value) stores. Output is
// bitwise identical to REPS=1; only HBM write traffic is multiplied.
__global__ __launch_bounds__(256) void fused_pe_kernel(const float* __restrict__ query,
                                                       const float* __restrict__ table,
                                                       const int* __restrict__ time_ids,
                                                       float* __restrict__ out) {
    __shared__ int   ts[KLEN];               // 4 KB
    __shared__ int   bmax[KLEN / 16];        // 256 B: bmax[i] = ts[16i+15]
    __shared__ short qth[2 * 64 * 8];        // A-frags [kstep][lane][j]    2 KB
    __shared__ short tbh[2 * 4 * 48 * 8];    // B-frags [kstep][quad][n][j] 6 KB
    __shared__ float pr[QTILE * PRS];        // 3 KB

    const int tid  = threadIdx.x;
    const int wave = tid >> 6;
    const int lane = tid & 63;
    const int tile = blockIdx.x;             // 0 .. B*H*64-1
    const int bh   = tile >> 6;
    const int qt_i = tile & 63;
    const int b    = bh >> 3;                // H = 8
    const int q0   = qt_i * QTILE;
    const int rowbase = bh * LQ + q0;

    // ---- Phase 1: staging ----
    {
        int4 tv = ((const int4*)(time_ids + b * KLEN))[tid];
        ((int4*)ts)[tid] = tv;
        if ((tid & 3) == 3) bmax[tid >> 2] = tv.w;   // block max (sorted)
    }
    {   // Q tile: float4 index tid covers element (m, 4c..4c+3)
        float4 v = ((const float4*)(query + (size_t)rowbase * DH))[tid];
        int m = tid >> 4, c = tid & 15;
        int kstep = c >> 3, quad = (c >> 1) & 3, jb = (c & 1) << 2;
        short4 hv = make_short4(f2bf(v.x), f2bf(v.y), f2bf(v.z), f2bf(v.w));
        *(short4*)(qth + ((kstep * 64 + quad * 16 + m) << 3) + jb) = hv;
    }
    for (int i = tid; i < NTAB * 16; i += 256) {   // table rows 0..32
        int n = i >> 4, c = i & 15;
        float4 v = ((const float4*)table)[i];
        int kstep = c >> 3, quad = (c >> 1) & 3, jb = (c & 1) << 2;
        short4 hv = make_short4(f2bf(v.x), f2bf(v.y), f2bf(v.z), f2bf(v.w));
        *(short4*)(tbh + (((kstep * 4 + quad) * 48 + n) << 3) + jb) = hv;
    }
    __syncthreads();                         // the only barrier

    // ---- Phase 2: MFMA proj, wave-private writes ----
    const int quad = lane >> 4;
    const int nlo  = lane & 15;
    f32x4 acc0 = {0.f, 0.f, 0.f, 0.f}, acc1 = acc0, acc2 = acc0;
#pragma unroll
    for (int kstep = 0; kstep < 2; ++kstep) {
        s16x8 a = *(const s16x8*)(qth + ((kstep * 64 + lane) << 3));
        const short* bbase = tbh + (((kstep * 4 + quad) * 48) << 3);
        s16x8 b0 = *(const s16x8*)(bbase + (nlo << 3));
        s16x8 b1 = *(const s16x8*)(bbase + ((nlo + 16) << 3));
        s16x8 b2 = *(const s16x8*)(bbase + (32 << 3));   // n=32 broadcast
        acc0 = __builtin_amdgcn_mfma_f32_16x16x32_bf16(a, b0, acc0, 0, 0, 0);
        acc1 = __builtin_amdgcn_mfma_f32_16x16x32_bf16(a, b1, acc1, 0, 0, 0);
        acc2 = __builtin_amdgcn_mfma_f32_16x16x32_bf16(a, b2, acc2, 0, 0, 0);
    }
    if (quad == wave) {                      // lanes holding rows 4w..4w+3
#pragma unroll
        for (int i = 0; i < 4; ++i) {
            int row = wave * 4 + i;
            pr[row * PRS + nlo]      = acc0[i];
            pr[row * PRS + 16 + nlo] = acc1[i];
            pr[row * PRS + 32]       = acc2[i];
        }
    }
    // no barrier: pr rows 4w..4w+3 written and read by wave w only

    // ---- Phase 3 (x REPS, idempotent): window + scalar chunks + nt stores ----
    for (int rep = 0; rep < REPS; ++rep) {
#pragma unroll
        for (int r = 0; r < 4; ++r) {
            const int row = wave * 4 + r;
            const int tq  = ts[q0 + row];        // LDS broadcast (wave-uniform)
            const float* prr = pr + row * PRS;
            const float p0  = prr[0];            // LDS broadcast
            const float p32 = prr[32];           // LDS broadcast

            // klo = first k with ts[k] >= tq-15 ; khi = first k with ts[k] >= tq+16
            const int thA = tq - (MAX_REL - 1);
            const int thB = tq + MAX_REL;

            const int eL = bmax[lane];
            const unsigned long long mA = __ballot(eL >= thA);
            const unsigned long long mB = __ballot(eL >= thB);
            const int bA = mA ? (__ffsll(mA) - 1) : 64;
            const int bB = mB ? (__ffsll(mB) - 1) : 64;
            const int eA = ts[((bA & 63) << 4) | (lane & 15)];
            const int eB = ts[((bB & 63) << 4) | (lane & 15)];
            const unsigned long long m2A = __ballot(lane < 16 && eA >= thA);
            const unsigned long long m2B = __ballot(lane < 16 && eB >= thB);
            int klo = (bA == 64) ? KLEN : ((bA << 4) + __ffsll(m2A) - 1);
            int khi = (bB == 64) ? KLEN : ((bB << 4) + __ffsll(m2B) - 1);
            klo = __builtin_amdgcn_readfirstlane(klo);
            khi = __builtin_amdgcn_readfirstlane(khi);

            float* op = out + (size_t)(rowbase + row) * KLEN + (lane << 2);
            const f32x4 v0  = {p0,  p0,  p0,  p0};
            const f32x4 v32 = {p32, p32, p32, p32};
#pragma unroll
            for (int c = 0; c < 4; ++c) {
                const int kb = c << 8;           // chunk covers k in [kb, kb+255]
                f32x4* dst = (f32x4*)(op + kb);
                if (khi <= kb) {                 // wave-uniform scalar branch
                    __builtin_nontemporal_store(v32, dst);
                } else if (klo >= kb + 256) {
                    __builtin_nontemporal_store(v0, dst);
                } else {                         // straddling chunk (~1 per row)
                    int4 tk = ((const int4*)ts)[(kb >> 2) + lane];
                    int i0 = min(max(tk.x - tq, -MAX_REL), MAX_REL) + MAX_REL;
                    int i1 = min(max(tk.y - tq, -MAX_REL), MAX_REL) + MAX_REL;
                    int i2 = min(max(tk.z - tq, -MAX_REL), MAX_REL) + MAX_REL;
                    int i3 = min(max(tk.w - tq, -MAX_REL), MAX_REL) + MAX_REL;
                    f32x4 v = {prr[i0], prr[i1], prr[i2], prr[i3]};
                    __builtin_nontemporal_store(v, dst);
                }
            }
        }
        asm volatile("" ::: "memory");       // keep the repeated stores alive
    }
}

extern "C" void kernel_launch(void* const* d_in, const int* in_sizes, int n_in,
                              void* d_out, int out_size, void* d_ws, size_t ws_size,
                              hipStream_t stream) {
    const float* query    = (const float*)d_in[0];   // (B,H,LQ,DH) f32
    const float* table    = (const float*)d_in[1];   // (33, DH) f32
    const int*   time_ids = (const int*)d_in[2];     // (B, KLEN) int32
    float* out = (float*)d_out;                      // (B,H,LQ,KLEN) f32

    fused_pe_kernel<<<B * H * (LQ / QTILE), 256, 0, stream>>>(query, table, time_ids, out);
}

// Round 8
// 145.181 us; speedup vs baseline: 1.5377x; 1.5377x over previous
//
#include <hip/hip_runtime.h>

#define MAX_REL 16
#define NTAB    33          // 2*MAX_REL+1
#define B       4
#define H       8
#define LQ      1024
#define DH      64
#define KLEN    1024
#define QTILE   16          // q rows per block (4 per wave)
#define PRS     48          // pr row stride (floats)

typedef short s16x8 __attribute__((ext_vector_type(8)));   // 8 bf16 (4 VGPRs)
typedef float f32x4 __attribute__((ext_vector_type(4)));   // MFMA acc / store vec

// round-to-nearest-even f32 -> bf16
static __device__ __forceinline__ short f2bf(float f) {
    unsigned u = __float_as_uint(f);
    unsigned r = (u + 0x7FFFu + ((u >> 16) & 1u)) >> 16;
    return (short)r;
}

// One block = (b, h, 16 q-rows); 4 waves.  VERIFIED R3 STRUCTURE (2048 blocks)
// — reverted after three failed TPB=4 builds (R5-R7, unexplained mapping-class
// corruption; 2048-block builds have never failed).
// Two safe edits vs R3: (1) plain stores instead of nontemporal (let L3 absorb
// the 134MB stream; nt forces synchronous HBM drain), (2) query load issued
// first in phase 1 (heads the longest dependency chain).
__global__ __launch_bounds__(256) void fused_pe_kernel(const float* __restrict__ query,
                                                       const float* __restrict__ table,
                                                       const int* __restrict__ time_ids,
                                                       float* __restrict__ out) {
    __shared__ int   ts[KLEN];               // 4 KB
    __shared__ int   bmax[KLEN / 16];        // 256 B: bmax[i] = ts[16i+15]
    __shared__ short qth[2 * 64 * 8];        // A-frags [kstep][lane][j]    2 KB
    __shared__ short tbh[2 * 4 * 48 * 8];    // B-frags [kstep][quad][n][j] 6 KB
    __shared__ float pr[QTILE * PRS];        // 3 KB

    const int tid  = threadIdx.x;
    const int wave = tid >> 6;
    const int lane = tid & 63;
    const int tile = blockIdx.x;             // 0 .. B*H*64-1
    const int bh   = tile >> 6;
    const int qt_i = tile & 63;
    const int b    = bh >> 3;                // H = 8
    const int q0   = qt_i * QTILE;
    const int rowbase = bh * LQ + q0;

    // ---- Phase 1: staging (query load issued first: longest chain) ----
    {   // Q tile: float4 index tid covers element (m, 4c..4c+3)
        float4 v = ((const float4*)(query + (size_t)rowbase * DH))[tid];
        int m = tid >> 4, c = tid & 15;
        int kstep = c >> 3, quad = (c >> 1) & 3, jb = (c & 1) << 2;
        short4 hv = make_short4(f2bf(v.x), f2bf(v.y), f2bf(v.z), f2bf(v.w));
        *(short4*)(qth + ((kstep * 64 + quad * 16 + m) << 3) + jb) = hv;
    }
    {
        int4 tv = ((const int4*)(time_ids + b * KLEN))[tid];
        ((int4*)ts)[tid] = tv;
        if ((tid & 3) == 3) bmax[tid >> 2] = tv.w;   // block max (sorted)
    }
    for (int i = tid; i < NTAB * 16; i += 256) {   // table rows 0..32
        int n = i >> 4, c = i & 15;
        float4 v = ((const float4*)table)[i];
        int kstep = c >> 3, quad = (c >> 1) & 3, jb = (c & 1) << 2;
        short4 hv = make_short4(f2bf(v.x), f2bf(v.y), f2bf(v.z), f2bf(v.w));
        *(short4*)(tbh + (((kstep * 4 + quad) * 48 + n) << 3) + jb) = hv;
    }
    __syncthreads();                         // the only barrier

    // ---- Phase 2: MFMA proj, wave-private writes ----
    const int quad = lane >> 4;
    const int nlo  = lane & 15;
    f32x4 acc0 = {0.f, 0.f, 0.f, 0.f}, acc1 = acc0, acc2 = acc0;
#pragma unroll
    for (int kstep = 0; kstep < 2; ++kstep) {
        s16x8 a = *(const s16x8*)(qth + ((kstep * 64 + lane) << 3));
        const short* bbase = tbh + (((kstep * 4 + quad) * 48) << 3);
        s16x8 b0 = *(const s16x8*)(bbase + (nlo << 3));
        s16x8 b1 = *(const s16x8*)(bbase + ((nlo + 16) << 3));
        s16x8 b2 = *(const s16x8*)(bbase + (32 << 3));   // n=32 broadcast
        acc0 = __builtin_amdgcn_mfma_f32_16x16x32_bf16(a, b0, acc0, 0, 0, 0);
        acc1 = __builtin_amdgcn_mfma_f32_16x16x32_bf16(a, b1, acc1, 0, 0, 0);
        acc2 = __builtin_amdgcn_mfma_f32_16x16x32_bf16(a, b2, acc2, 0, 0, 0);
    }
    if (quad == wave) {                      // lanes holding rows 4w..4w+3
#pragma unroll
        for (int i = 0; i < 4; ++i) {
            int row = wave * 4 + i;
            pr[row * PRS + nlo]      = acc0[i];
            pr[row * PRS + 16 + nlo] = acc1[i];
            pr[row * PRS + 32]       = acc2[i];
        }
    }
    // no barrier: pr rows 4w..4w+3 written and read by wave w only

    // ---- Phase 3: per-row window + scalar-classified chunks + plain stores ----
#pragma unroll
    for (int r = 0; r < 4; ++r) {
        const int row = wave * 4 + r;
        const int tq  = ts[q0 + row];        // LDS broadcast (wave-uniform)
        const float* prr = pr + row * PRS;
        const float p0  = prr[0];            // LDS broadcast
        const float p32 = prr[32];           // LDS broadcast

        // klo = first k with ts[k] >= tq-15 ; khi = first k with ts[k] >= tq+16
        const int thA = tq - (MAX_REL - 1);
        const int thB = tq + MAX_REL;

        const int eL = bmax[lane];
        const unsigned long long mA = __ballot(eL >= thA);
        const unsigned long long mB = __ballot(eL >= thB);
        const int bA = mA ? (__ffsll(mA) - 1) : 64;
        const int bB = mB ? (__ffsll(mB) - 1) : 64;
        const int eA = ts[((bA & 63) << 4) | (lane & 15)];
        const int eB = ts[((bB & 63) << 4) | (lane & 15)];
        const unsigned long long m2A = __ballot(lane < 16 && eA >= thA);
        const unsigned long long m2B = __ballot(lane < 16 && eB >= thB);
        int klo = (bA == 64) ? KLEN : ((bA << 4) + __ffsll(m2A) - 1);
        int khi = (bB == 64) ? KLEN : ((bB << 4) + __ffsll(m2B) - 1);
        klo = __builtin_amdgcn_readfirstlane(klo);   // SGPR -> scalar branches
        khi = __builtin_amdgcn_readfirstlane(khi);

        float* op = out + (size_t)(rowbase + row) * KLEN + (lane << 2);
        const f32x4 v0  = {p0,  p0,  p0,  p0};
        const f32x4 v32 = {p32, p32, p32, p32};
#pragma unroll
        for (int c = 0; c < 4; ++c) {
            const int kb = c << 8;           // chunk covers k in [kb, kb+255]
            f32x4* dst = (f32x4*)(op + kb);
            if (khi <= kb) {                 // wave-uniform scalar branch
                *dst = v32;
            } else if (klo >= kb + 256) {
                *dst = v0;
            } else {                         // straddling chunk (~1 per row)
                int4 tk = ((const int4*)ts)[(kb >> 2) + lane];
                int i0 = min(max(tk.x - tq, -MAX_REL), MAX_REL) + MAX_REL;
                int i1 = min(max(tk.y - tq, -MAX_REL), MAX_REL) + MAX_REL;
                int i2 = min(max(tk.z - tq, -MAX_REL), MAX_REL) + MAX_REL;
                int i3 = min(max(tk.w - tq, -MAX_REL), MAX_REL) + MAX_REL;
                f32x4 v = {prr[i0], prr[i1], prr[i2], prr[i3]};
                *dst = v;
            }
        }
    }
}

extern "C" void kernel_launch(void* const* d_in, const int* in_sizes, int n_in,
                              void* d_out, int out_size, void* d_ws, size_t ws_size,
                              hipStream_t stream) {
    const float* query    = (const float*)d_in[0];   // (B,H,LQ,DH) f32
    const float* table    = (const float*)d_in[1];   // (33, DH) f32
    const int*   time_ids = (const int*)d_in[2];     // (B, KLEN) int32
    float* out = (float*)d_out;                      // (B,H,LQ,KLEN) f32

    fused_pe_kernel<<<B * H * (LQ / QTILE), 256, 0, stream>>>(query, table, time_ids, out);
}

// Round 9
// 144.023 us; speedup vs baseline: 1.5500x; 1.0080x over previous
//
#include <hip/hip_runtime.h>

#define MAX_REL 16
#define NTAB    33          // 2*MAX_REL+1
#define B       4
#define H       8
#define LQ      1024
#define DH      64
#define KLEN    1024
#define QTILE   16          // q rows per block (4 per wave)
#define PRS     48          // pr row stride (floats)

typedef short s16x8 __attribute__((ext_vector_type(8)));   // 8 bf16 (4 VGPRs)
typedef float f32x4 __attribute__((ext_vector_type(4)));   // MFMA acc / store vec

// round-to-nearest-even f32 -> bf16
static __device__ __forceinline__ short f2bf(float f) {
    unsigned u = __float_as_uint(f);
    unsigned r = (u + 0x7FFFu + ((u >> 16) & 1u)) >> 16;
    return (short)r;
}

// One block = (b, h, 16 q-rows); 4 waves. VERIFIED R8 STRUCTURE (2048 blocks).
// R9 change (pure reordering, no new sync/mapping): phase 3 batches ALL
// per-row LDS reads (tq/p0/p32 x4 rows) and all 4 window searches BEFORE the
// store loop, and hoists row-invariant bmax[lane]. Steady-state store issue
// then has zero LDS dependencies on the fast path (~13/16 chunks), so store
// bursts aren't stalled by interleaved lgkmcnt waits.
__global__ __launch_bounds__(256) void fused_pe_kernel(const float* __restrict__ query,
                                                       const float* __restrict__ table,
                                                       const int* __restrict__ time_ids,
                                                       float* __restrict__ out) {
    __shared__ int   ts[KLEN];               // 4 KB
    __shared__ int   bmax[KLEN / 16];        // 256 B: bmax[i] = ts[16i+15]
    __shared__ short qth[2 * 64 * 8];        // A-frags [kstep][lane][j]    2 KB
    __shared__ short tbh[2 * 4 * 48 * 8];    // B-frags [kstep][quad][n][j] 6 KB
    __shared__ float pr[QTILE * PRS];        // 3 KB

    const int tid  = threadIdx.x;
    const int wave = tid >> 6;
    const int lane = tid & 63;
    const int tile = blockIdx.x;             // 0 .. B*H*64-1
    const int bh   = tile >> 6;
    const int qt_i = tile & 63;
    const int b    = bh >> 3;                // H = 8
    const int q0   = qt_i * QTILE;
    const int rowbase = bh * LQ + q0;

    // ---- Phase 1: staging (query load issued first: longest chain) ----
    {   // Q tile: float4 index tid covers element (m, 4c..4c+3)
        float4 v = ((const float4*)(query + (size_t)rowbase * DH))[tid];
        int m = tid >> 4, c = tid & 15;
        int kstep = c >> 3, quad = (c >> 1) & 3, jb = (c & 1) << 2;
        short4 hv = make_short4(f2bf(v.x), f2bf(v.y), f2bf(v.z), f2bf(v.w));
        *(short4*)(qth + ((kstep * 64 + quad * 16 + m) << 3) + jb) = hv;
    }
    {
        int4 tv = ((const int4*)(time_ids + b * KLEN))[tid];
        ((int4*)ts)[tid] = tv;
        if ((tid & 3) == 3) bmax[tid >> 2] = tv.w;   // block max (sorted)
    }
    for (int i = tid; i < NTAB * 16; i += 256) {   // table rows 0..32
        int n = i >> 4, c = i & 15;
        float4 v = ((const float4*)table)[i];
        int kstep = c >> 3, quad = (c >> 1) & 3, jb = (c & 1) << 2;
        short4 hv = make_short4(f2bf(v.x), f2bf(v.y), f2bf(v.z), f2bf(v.w));
        *(short4*)(tbh + (((kstep * 4 + quad) * 48 + n) << 3) + jb) = hv;
    }
    __syncthreads();                         // the only barrier

    // ---- Phase 2: MFMA proj, wave-private writes ----
    const int quad = lane >> 4;
    const int nlo  = lane & 15;
    f32x4 acc0 = {0.f, 0.f, 0.f, 0.f}, acc1 = acc0, acc2 = acc0;
#pragma unroll
    for (int kstep = 0; kstep < 2; ++kstep) {
        s16x8 a = *(const s16x8*)(qth + ((kstep * 64 + lane) << 3));
        const short* bbase = tbh + (((kstep * 4 + quad) * 48) << 3);
        s16x8 b0 = *(const s16x8*)(bbase + (nlo << 3));
        s16x8 b1 = *(const s16x8*)(bbase + ((nlo + 16) << 3));
        s16x8 b2 = *(const s16x8*)(bbase + (32 << 3));   // n=32 broadcast
        acc0 = __builtin_amdgcn_mfma_f32_16x16x32_bf16(a, b0, acc0, 0, 0, 0);
        acc1 = __builtin_amdgcn_mfma_f32_16x16x32_bf16(a, b1, acc1, 0, 0, 0);
        acc2 = __builtin_amdgcn_mfma_f32_16x16x32_bf16(a, b2, acc2, 0, 0, 0);
    }
    if (quad == wave) {                      // lanes holding rows 4w..4w+3
#pragma unroll
        for (int i = 0; i < 4; ++i) {
            int row = wave * 4 + i;
            pr[row * PRS + nlo]      = acc0[i];
            pr[row * PRS + 16 + nlo] = acc1[i];
            pr[row * PRS + 32]       = acc2[i];
        }
    }
    // no barrier: pr rows 4w..4w+3 written and read by wave w only

    // ---- Phase 3a: batch per-row LDS reads + window searches (all 4 rows) ----
    const int eL = bmax[lane];               // row-invariant: read once
    int   tqs[4];  float p0s[4], p32s[4];
#pragma unroll
    for (int r = 0; r < 4; ++r) {            // 12 LDS reads issued together
        const int row = wave * 4 + r;
        tqs[r]  = ts[q0 + row];              // LDS broadcast (wave-uniform)
        p0s[r]  = pr[row * PRS];             // LDS broadcast
        p32s[r] = pr[row * PRS + 32];        // LDS broadcast
    }
    int klos[4], khis[4];
#pragma unroll
    for (int r = 0; r < 4; ++r) {
        // klo = first k with ts[k] >= tq-15 ; khi = first k with ts[k] >= tq+16
        const int thA = tqs[r] - (MAX_REL - 1);
        const int thB = tqs[r] + MAX_REL;
        const unsigned long long mA = __ballot(eL >= thA);
        const unsigned long long mB = __ballot(eL >= thB);
        const int bA = mA ? (__ffsll(mA) - 1) : 64;
        const int bB = mB ? (__ffsll(mB) - 1) : 64;
        const int eA = ts[((bA & 63) << 4) | (lane & 15)];
        const int eB = ts[((bB & 63) << 4) | (lane & 15)];
        const unsigned long long m2A = __ballot(lane < 16 && eA >= thA);
        const unsigned long long m2B = __ballot(lane < 16 && eB >= thB);
        int klo = (bA == 64) ? KLEN : ((bA << 4) + __ffsll(m2A) - 1);
        int khi = (bB == 64) ? KLEN : ((bB << 4) + __ffsll(m2B) - 1);
        klos[r] = __builtin_amdgcn_readfirstlane(klo);   // SGPR -> scalar branches
        khis[r] = __builtin_amdgcn_readfirstlane(khi);
    }

    // ---- Phase 3b: store loop — fast-path chunks touch no LDS ----
#pragma unroll
    for (int r = 0; r < 4; ++r) {
        const int row = wave * 4 + r;
        const int tq  = tqs[r];
        const int klo = klos[r], khi = khis[r];
        const float* prr = pr + row * PRS;
        float* op = out + (size_t)(rowbase + row) * KLEN + (lane << 2);
        const f32x4 v0  = {p0s[r],  p0s[r],  p0s[r],  p0s[r]};
        const f32x4 v32 = {p32s[r], p32s[r], p32s[r], p32s[r]};
#pragma unroll
        for (int c = 0; c < 4; ++c) {
            const int kb = c << 8;           // chunk covers k in [kb, kb+255]
            f32x4* dst = (f32x4*)(op + kb);
            if (khi <= kb) {                 // wave-uniform scalar branch
                *dst = v32;
            } else if (klo >= kb + 256) {
                *dst = v0;
            } else {                         // straddling chunk (~1 per row)
                int4 tk = ((const int4*)ts)[(kb >> 2) + lane];
                int i0 = min(max(tk.x - tq, -MAX_REL), MAX_REL) + MAX_REL;
                int i1 = min(max(tk.y - tq, -MAX_REL), MAX_REL) + MAX_REL;
                int i2 = min(max(tk.z - tq, -MAX_REL), MAX_REL) + MAX_REL;
                int i3 = min(max(tk.w - tq, -MAX_REL), MAX_REL) + MAX_REL;
                f32x4 v = {prr[i0], prr[i1], prr[i2], prr[i3]};
                *dst = v;
            }
        }
    }
}

extern "C" void kernel_launch(void* const* d_in, const int* in_sizes, int n_in,
                              void* d_out, int out_size, void* d_ws, size_t ws_size,
                              hipStream_t stream) {
    const float* query    = (const float*)d_in[0];   // (B,H,LQ,DH) f32
    const float* table    = (const float*)d_in[1];   // (33, DH) f32
    const int*   time_ids = (const int*)d_in[2];     // (B, KLEN) int32
    float* out = (float*)d_out;                      // (B,H,LQ,KLEN) f32

    fused_pe_kernel<<<B * H * (LQ / QTILE), 256, 0, stream>>>(query, table, time_ids, out);
}